// Round 18
// baseline (1036.601 us; speedup 1.0000x reference)
//
#include <hip/hip_runtime.h>
#include <stdint.h>

typedef int i32x4  __attribute__((ext_vector_type(4)));
typedef int i32x16 __attribute__((ext_vector_type(16)));

constexpr int Bsz  = 4096;
constexpr int Tst  = 20;
constexpr int Fin  = 2000;
constexpr int H1   = 512;
constexpr int H2   = 128;
constexpr int NOUT = 10;
constexpr int FW   = 64;     // words per layer-1 spike row (2048 bits = 256 bytes)

// ---------------- Threefry-2x32-20, key = jax.random.key(1) = [0,1] ----------------
#define TFR(r) { x0 += x1; x1 = __builtin_rotateleft32(x1, (r)) ^ x0; }
__device__ __forceinline__ uint32_t tf_bits(uint32_t c1) {
  const uint32_t k1 = 1u, k2 = 0x1BD11BDBu;   // k0 = 0
  uint32_t x0 = 0u, x1 = c1 + k1;
  TFR(13) TFR(15) TFR(26) TFR(6)   x0 += k1; x1 += k2 + 1u;
  TFR(17) TFR(29) TFR(16) TFR(24)  x0 += k2; x1 += 2u;
  TFR(13) TFR(15) TFR(26) TFR(6)              x1 += k1 + 3u;
  TFR(17) TFR(29) TFR(16) TFR(24)  x0 += k1; x1 += k2 + 4u;
  TFR(13) TFR(15) TFR(26) TFR(6)   x0 += k2; x1 += 5u;
  return x0 ^ x1;                              // partitionable: out0 ^ out1
}
#undef TFR

// Partitionable threefry (verified round 2): spike iff (bits>>9) < ceil(p*2^23).
// VALU-issue-bound ~330us (round 13) — accepted.
__global__ __launch_bounds__(256) void spikegen4(const float* __restrict__ x,
                                                 uint32_t* __restrict__ sbits) {
  int gid = blockIdx.x * 256 + threadIdx.x;   // 4096*256 threads
  int w8 = gid & 255;                         // byte index in 256-byte row
  int b  = gid >> 8;
  int f0 = w8 * 8;
  const float* xr = x + (size_t)b * Fin;
  uint32_t T[8];
#pragma unroll
  for (int j = 0; j < 8; ++j) {
    int f = f0 + j;
    float p = (f < Fin) ? xr[f] : 0.0f;
    T[j] = (uint32_t)ceilf(p * 8388608.0f);   // ceil(p * 2^23), exact
    asm volatile("" : "+v"(T[j]));            // pin: no remat into t-loop
  }
  uint8_t* sb = (uint8_t*)sbits + (size_t)(b * Tst) * 256 + w8;
  uint32_t ib = (uint32_t)(b * Tst) * (uint32_t)Fin + (uint32_t)f0;
#pragma unroll 1
  for (int t = 0; t < Tst; ++t) {
    uint32_t bits = 0;
#pragma unroll
    for (int j = 0; j < 8; ++j) {
      uint32_t m = tf_bits(ib + (uint32_t)j) >> 9;
      bits |= ((m - T[j]) >> 31) << j;        // sub, shr31, lshl_or
    }
    *sb = (uint8_t)bits;
    sb += 256;
    ib += (uint32_t)Fin;
  }
}

// Decompose W into 4 balanced base-256 int8 digits on grid 2^-33, fragment-tiled:
// Btl[s][nt][kst][ (khalf*32+col)*16 + j ].
__global__ void wslice_i8(const float* __restrict__ W, int O, int K, int KPAD,
                          int8_t* __restrict__ Btl) {
  int idx = blockIdx.x * 256 + threadIdx.x;
  if (idx >= O * KPAD) return;
  int o = idx / KPAD, f = idx % KPAD;
  long long wi = 0;
  if (f < K) wi = llround((double)W[(size_t)o * K + f] * 8589934592.0);  // 2^33
  int nt = o >> 5, c = o & 31, kst = f >> 5, kh = (f >> 4) & 1, j = f & 15;
  int NT = O >> 5, KST = KPAD >> 5;
  size_t base = (((size_t)nt * KST + kst) << 10) + (size_t)(kh * 32 + c) * 16 + j;
  size_t sstride = ((size_t)NT * KST) << 10;
  long long rem = wi;
#pragma unroll
  for (int s = 0; s < 4; ++s) {
    int d;
    if (s < 3) { d = (int)(int8_t)(rem & 0xff); rem = (rem - d) >> 8; }
    else d = (int)rem;                       // |d| <= ~52
    Btl[base + (size_t)s * sstride] = (int8_t)d;
  }
}

// Expand 16 spike bits -> 16 i8 (0/1), multiply bit-spread (round-13 verified).
__device__ __forceinline__ uint4 expand16u(uint32_t m) {
  const uint32_t MUL = 0x00204081u, MSK = 0x01010101u;
  return make_uint4(
      ((m         & 0xFu) * MUL) & MSK,
      (((m >> 4)  & 0xFu) * MUL) & MSK,
      (((m >> 8)  & 0xFu) * MUL) & MSK,
      (((m >> 12) & 0xFu) * MUL) & MSK);
}

// Pre-expand spike bits -> fragment-tiled i8 A (verified round 16):
// Ai8[((rt*KST+kst)*2+m)*1024 + L*16] = expand16(bits16(row=rowBase+rt*64+m*32+(L&31),
// kst, khalf=L>>5)).
template <int KST>
__global__ __launch_bounds__(256) void aexp(const uint32_t* __restrict__ bits,
                                            int awords, int rowBase,
                                            uint8_t* __restrict__ Ai8) {
  int tid = blockIdx.x * 256 + threadIdx.x;
  int L = tid & 63;
  int idx = tid >> 6;                 // (rt*KST + kst)*2 + m
  int m = idx & 1;
  int rk = idx >> 1;                  // rt*KST + kst
  int kst = rk & (KST - 1);
  int rt = rk / KST;
  int row = rowBase + rt * 64 + m * 32 + (L & 31);
  uint32_t b16 = *(const uint16_t*)((const uint8_t*)bits +
                  (size_t)row * (size_t)(awords * 4) + kst * 4 + (L >> 5) * 2);
  *(uint4*)(Ai8 + (size_t)tid * 16) = expand16u(b16);
}

// ---------------- i8 MFMA slice GEMM v3 ----------------
typedef const __attribute__((address_space(1))) uint32_t* gas_ptr;
typedef __attribute__((address_space(3))) uint32_t* las_ptr;
__device__ __forceinline__ void gld16(const void* g, void* l) {
  __builtin_amdgcn_global_load_lds((gas_ptr)g, (las_ptr)l, 16, 0, 0);
}

// Barrier-free per-wave pipeline (verified r12-14/17) with PRE-EXPANDED A:
// A fragments loaded global->VGPR 1 round ahead (issued BEFORE B staging so the
// steady-state entry vmcnt(4) drains A(r)+B(r)); B staged wave-private via gld16
// as before. Removes the 4x-redundant expand16 (~52 VALU inst/round -> ~8).
template <int KPAD, int O>
__global__ __launch_bounds__(256, 4) void gemm_i8v3(
    const uint8_t* __restrict__ Ai8, const int8_t* __restrict__ Btl,
    const float* __restrict__ bias, float* __restrict__ Cout) {
  constexpr int KST = KPAD / 32;
  constexpr int NR  = KST / 2;            // rounds (2 K-steps each), even, >= 4
  constexpr int NT  = O / 32;
  __shared__ __align__(16) char smem[32768];   // 4 waves x [2 buf][2 kk][2 nt][1KB]
  const int tid = threadIdx.x;
  const int lane = tid & 63;
  const int s = tid >> 6;                 // wave id = slice id
  const int rt = blockIdx.x;
  const int col0 = blockIdx.y * 64;
  const int nt0 = blockIdx.y * 2;

  i32x16 acc[2][2] = {};

  const uint8_t* asrc = Ai8 + ((size_t)rt * KST * 2) * 1024 + (size_t)lane * 16;
  const int8_t* bsrc0 = Btl + ((((size_t)s * NT + nt0) * KST) << 10) + (size_t)lane * 16;
  const int8_t* bsrc1 = Btl + ((((size_t)s * NT + nt0 + 1) * KST) << 10) + (size_t)lane * 16;
  char* sBs = smem + s * 8192;            // this wave's private region

  uint4 A0[4], A1[4];   // [ (kk,m) = (0,0),(0,1),(1,0),(1,1) ] for one round

#define LOADA(Ar, r) do {                                                                  \
    Ar[0] = *(const uint4*)(asrc + (((size_t)(2*(r))     * 2 + 0) << 10));                 \
    Ar[1] = *(const uint4*)(asrc + (((size_t)(2*(r))     * 2 + 1) << 10));                 \
    Ar[2] = *(const uint4*)(asrc + (((size_t)(2*(r) + 1) * 2 + 0) << 10));                 \
    Ar[3] = *(const uint4*)(asrc + (((size_t)(2*(r) + 1) * 2 + 1) << 10));                 \
  } while (0)

#define STAGEB(buf, r) do {                                                                \
    gld16(bsrc0 + ((size_t)(2*(r))   << 10), sBs + (buf) * 4096 +        lane * 16);       \
    gld16(bsrc1 + ((size_t)(2*(r))   << 10), sBs + (buf) * 4096 + 1024 + lane * 16);       \
    gld16(bsrc0 + ((size_t)(2*(r)+1) << 10), sBs + (buf) * 4096 + 2048 + lane * 16);       \
    gld16(bsrc1 + ((size_t)(2*(r)+1) << 10), sBs + (buf) * 4096 + 3072 + lane * 16);       \
  } while (0)

  // ROUND r: consumes Acur (loaded last round) + B(r) from LDS; issues A(r+1)
  // (first!) then B(r+2) staging. Entry wait: vmcnt(4) steady, 0 on last round.
#define ROUND(r, WAITN, Acur, Anxt) do {                                                   \
    asm volatile("s_waitcnt vmcnt(" #WAITN ")" ::: "memory");                              \
    __builtin_amdgcn_sched_barrier(0);                                                     \
    const char* bb = sBs + ((r) & 1) * 4096 + lane * 16;                                   \
    uint4 b00 = *(const uint4*)(bb);                                                       \
    uint4 b01 = *(const uint4*)(bb + 1024);                                                \
    uint4 b10 = *(const uint4*)(bb + 2048);                                                \
    uint4 b11 = *(const uint4*)(bb + 3072);                                                \
    asm volatile("s_waitcnt lgkmcnt(0)" ::: "memory");                                     \
    if ((r) + 1 < NR) LOADA(Anxt, (r) + 1);                                                \
    if ((r) + 2 < NR) STAGEB((r) & 1, (r) + 2);                                            \
    i32x4 a00 = __builtin_bit_cast(i32x4, Acur[0]);  /* kk0, m0 */                         \
    i32x4 a10 = __builtin_bit_cast(i32x4, Acur[1]);  /* kk0, m1 */                         \
    i32x4 a01 = __builtin_bit_cast(i32x4, Acur[2]);  /* kk1, m0 */                         \
    i32x4 a11 = __builtin_bit_cast(i32x4, Acur[3]);  /* kk1, m1 */                         \
    i32x4 c00 = __builtin_bit_cast(i32x4, b00), c01 = __builtin_bit_cast(i32x4, b01);      \
    i32x4 c10 = __builtin_bit_cast(i32x4, b10), c11 = __builtin_bit_cast(i32x4, b11);      \
    __builtin_amdgcn_s_setprio(1);                                                         \
    acc[0][0] = __builtin_amdgcn_mfma_i32_32x32x32_i8(a00, c00, acc[0][0], 0, 0, 0);       \
    acc[0][1] = __builtin_amdgcn_mfma_i32_32x32x32_i8(a00, c01, acc[0][1], 0, 0, 0);       \
    acc[1][0] = __builtin_amdgcn_mfma_i32_32x32x32_i8(a10, c00, acc[1][0], 0, 0, 0);       \
    acc[1][1] = __builtin_amdgcn_mfma_i32_32x32x32_i8(a10, c01, acc[1][1], 0, 0, 0);       \
    acc[0][0] = __builtin_amdgcn_mfma_i32_32x32x32_i8(a01, c10, acc[0][0], 0, 0, 0);       \
    acc[0][1] = __builtin_amdgcn_mfma_i32_32x32x32_i8(a01, c11, acc[0][1], 0, 0, 0);       \
    acc[1][0] = __builtin_amdgcn_mfma_i32_32x32x32_i8(a11, c10, acc[1][0], 0, 0, 0);       \
    acc[1][1] = __builtin_amdgcn_mfma_i32_32x32x32_i8(a11, c11, acc[1][1], 0, 0, 0);       \
    __builtin_amdgcn_s_setprio(0);                                                         \
  } while (0)

  // Prologue: A(0) FIRST (so vmcnt(4) at ROUND(0) drains A(0)+B(0)), then B(0),B(1).
  LOADA(A0, 0);
  STAGEB(0, 0);
  STAGEB(1, 1);

#pragma unroll 1
  for (int g = 0; g < NR / 2 - 1; ++g) {
    ROUND(2 * g,     4, A0, A1);
    ROUND(2 * g + 1, 4, A1, A0);
  }
  ROUND(NR - 2, 4, A0, A1);
  ROUND(NR - 1, 0, A1, A0);
#undef ROUND
#undef STAGEB
#undef LOADA

  // Epilogue: i64 combine of the 4 slices via LDS, f32 output.
  // FULLY UNROLLED acc indices (rule #20).
  int* red = (int*)smem;   // [4][64 rows][32 cols] = 32KB
#pragma unroll
  for (int n = 0; n < 2; ++n) {
    __syncthreads();
#pragma unroll
    for (int m = 0; m < 2; ++m)
#pragma unroll
      for (int r = 0; r < 16; ++r) {
        int row = m * 32 + (r & 3) + ((r >> 2) << 3) + ((lane >> 5) << 2);
        red[(s * 64 + row) * 32 + (lane & 31)] = acc[m][n][r];
      }
    __syncthreads();
    for (int e = tid; e < 2048; e += 256) {
      int row = e >> 5, c = e & 31;
      long long v = 0;
#pragma unroll
      for (int s4 = 0; s4 < 4; ++s4)
        v += (long long)red[(s4 * 64 + row) * 32 + c] * (1LL << (8 * s4));
      int col = col0 + n * 32 + c;
      Cout[(size_t)(rt * 64 + row) * O + col] = (float)((double)v * 0x1p-33 + (double)bias[col]);
    }
  }
}

// LIF layer 1: one block per batch row of chunk, 512 threads = H1 neurons.
__global__ __launch_bounds__(512) void lif1(const float* __restrict__ inp1,
                                            uint32_t* __restrict__ spk1, int bBase) {
  int b_local = blockIdx.x;
  int o = threadIdx.x;
  int b = bBase + b_local;
  double mem = 0.0;
  for (int t = 0; t < Tst; ++t) {
    double inp = (double)inp1[((size_t)(b_local * Tst + t)) * H1 + o];
    mem = mem + (inp - mem) / 2.0;
    bool spk = (mem >= 1.0);
    unsigned long long m = __ballot(spk);
    if ((o & 63) == 0) {
      int wv = o >> 6;
      size_t base = ((size_t)(b * Tst + t)) * (H1 / 32);
      spk1[base + wv * 2]     = (uint32_t)(m & 0xffffffffu);
      spk1[base + wv * 2 + 1] = (uint32_t)(m >> 32);
    }
    if (spk) mem = 0.0;
  }
}

// LIF layer 2: one block per batch row of chunk; final membrane out (f64).
__global__ __launch_bounds__(128) void lif2(const float* __restrict__ inp2,
                                            double* __restrict__ mem2, int bBase) {
  int b_local = blockIdx.x;
  int o = threadIdx.x;
  double mem = 0.0;
  for (int t = 0; t < Tst; ++t) {
    double inp = (double)inp2[((size_t)(b_local * Tst + t)) * H2 + o];
    mem = mem + (inp - mem) / 2.0;
    if (mem >= 1.0) mem = 0.0;
  }
  mem2[(size_t)(bBase + b_local) * H2 + o] = mem;
}

// out = mem2 @ Wd^T + bd
__global__ void finalk(const double* __restrict__ mem2, const float* __restrict__ Wd,
                       const float* __restrict__ bd, float* __restrict__ out) {
  int gid = blockIdx.x * blockDim.x + threadIdx.x;
  if (gid >= Bsz * NOUT) return;
  int b = gid / NOUT, j = gid % NOUT;
  double s = (double)bd[j];
  const double* m = mem2 + (size_t)b * H2;
  const float* wr = Wd + (size_t)j * H2;
  for (int k = 0; k < H2; ++k) s = fma(m[k], (double)wr[k], s);
  out[gid] = (float)s;
}

extern "C" void kernel_launch(void* const* d_in, const int* in_sizes, int n_in,
                              void* d_out, int out_size, void* d_ws, size_t ws_size,
                              hipStream_t stream) {
  const float* x  = (const float*)d_in[0];
  const float* W1 = (const float*)d_in[1];
  const float* b1 = (const float*)d_in[2];
  const float* W2 = (const float*)d_in[3];
  const float* b2 = (const float*)d_in[4];
  const float* Wd = (const float*)d_in[5];
  const float* bd = (const float*)d_in[6];
  float* out = (float*)d_out;

  char* ws = (char*)d_ws;
  // Layout (bytes), ~77 MB total (same footprint as verified round 16):
  float*    inp   = (float*)   (ws);                  // 20,971,520 (chunk inp f32)
  uint8_t*  Ai8   = (uint8_t*) (ws + 20971520ull);    // 20,971,520 (chunk A i8, tiled)
  double*   mem2  = (double*)  (ws + 41943040ull);    //  4,194,304
  uint32_t* sbits = (uint32_t*)(ws + 46137344ull);    // 20,971,520
  uint32_t* spk1  = (uint32_t*)(ws + 67108864ull);    //  5,242,880
  int8_t*   Btl1  = (int8_t*)  (ws + 72351744ull);    //  4,194,304 (4*16*64*1024)
  int8_t*   Btl2  = (int8_t*)  (ws + 76546048ull);    //    262,144 (4*4*16*1024)

  // 1) exact Poisson spike train (bit-packed)
  spikegen4<<<dim3(Bsz), dim3(256), 0, stream>>>(x, sbits);

  // 2) weight digit decomposition (fragment-tiled, 4 slices, grid 2^-33)
  wslice_i8<<<dim3(512 * 2048 / 256), dim3(256), 0, stream>>>(W1, 512, 2000, 2048, Btl1);
  wslice_i8<<<dim3(128 * 512 / 256),  dim3(256), 0, stream>>>(W2, 128, 512, 512, Btl2);

  // 3) layer 1: 8 chunks of 10240 rows (512 batches); aexp + v3 GEMM (64x64 tiles)
  for (int c = 0; c < 8; ++c) {
    aexp<64><<<dim3(10240 * 64 * 2 / 256), dim3(256), 0, stream>>>(
        sbits, FW, c * 10240, Ai8);
    gemm_i8v3<2048, 512><<<dim3(160, 8), dim3(256), 0, stream>>>(Ai8, Btl1, b1, inp);
    lif1<<<dim3(512), dim3(H1), 0, stream>>>(inp, spk1, c * 512);
  }

  // 4) layer 2: 4 chunks of 20480 rows (1024 batches)
  for (int c = 0; c < 4; ++c) {
    aexp<16><<<dim3(20480 * 16 * 2 / 256), dim3(256), 0, stream>>>(
        spk1, H1 / 32, c * 20480, Ai8);
    gemm_i8v3<512, 128><<<dim3(320, 2), dim3(256), 0, stream>>>(Ai8, Btl2, b2, inp);
    lif2<<<dim3(1024), dim3(H2), 0, stream>>>(inp, mem2, c * 1024);
  }

  // 5) readout
  finalk<<<dim3((Bsz * NOUT + 255) / 256), dim3(256), 0, stream>>>(mem2, Wd, bd, out);
}

// Round 19
// 851.973 us; speedup vs baseline: 1.2167x; 1.2167x over previous
//
#include <hip/hip_runtime.h>
#include <stdint.h>

typedef int i32x4  __attribute__((ext_vector_type(4)));
typedef int i32x16 __attribute__((ext_vector_type(16)));

constexpr int Bsz  = 4096;
constexpr int Tst  = 20;
constexpr int Fin  = 2000;
constexpr int H1   = 512;
constexpr int H2   = 128;
constexpr int NOUT = 10;
constexpr int FW   = 64;     // words per layer-1 spike row (2048 bits = 256 bytes)

// ---------------- Threefry-2x32-20, key = jax.random.key(1) = [0,1] ----------------
#define TFR(r) { x0 += x1; x1 = __builtin_rotateleft32(x1, (r)) ^ x0; }
__device__ __forceinline__ uint32_t tf_bits(uint32_t c1) {
  const uint32_t k1 = 1u, k2 = 0x1BD11BDBu;   // k0 = 0
  uint32_t x0 = 0u, x1 = c1 + k1;
  TFR(13) TFR(15) TFR(26) TFR(6)   x0 += k1; x1 += k2 + 1u;
  TFR(17) TFR(29) TFR(16) TFR(24)  x0 += k2; x1 += 2u;
  TFR(13) TFR(15) TFR(26) TFR(6)              x1 += k1 + 3u;
  TFR(17) TFR(29) TFR(16) TFR(24)  x0 += k1; x1 += k2 + 4u;
  TFR(13) TFR(15) TFR(26) TFR(6)   x0 += k2; x1 += 5u;
  return x0 ^ x1;                              // partitionable: out0 ^ out1
}
#undef TFR

// Partitionable threefry (verified round 2): spike iff (bits>>9) < ceil(p*2^23).
// VALU-issue-bound ~330us (round 13) — accepted.
__global__ __launch_bounds__(256) void spikegen4(const float* __restrict__ x,
                                                 uint32_t* __restrict__ sbits) {
  int gid = blockIdx.x * 256 + threadIdx.x;   // 4096*256 threads
  int w8 = gid & 255;                         // byte index in 256-byte row
  int b  = gid >> 8;
  int f0 = w8 * 8;
  const float* xr = x + (size_t)b * Fin;
  uint32_t T[8];
#pragma unroll
  for (int j = 0; j < 8; ++j) {
    int f = f0 + j;
    float p = (f < Fin) ? xr[f] : 0.0f;
    T[j] = (uint32_t)ceilf(p * 8388608.0f);   // ceil(p * 2^23), exact
    asm volatile("" : "+v"(T[j]));            // pin: no remat into t-loop
  }
  uint8_t* sb = (uint8_t*)sbits + (size_t)(b * Tst) * 256 + w8;
  uint32_t ib = (uint32_t)(b * Tst) * (uint32_t)Fin + (uint32_t)f0;
#pragma unroll 1
  for (int t = 0; t < Tst; ++t) {
    uint32_t bits = 0;
#pragma unroll
    for (int j = 0; j < 8; ++j) {
      uint32_t m = tf_bits(ib + (uint32_t)j) >> 9;
      bits |= ((m - T[j]) >> 31) << j;        // sub, shr31, lshl_or
    }
    *sb = (uint8_t)bits;
    sb += 256;
    ib += (uint32_t)Fin;
  }
}

// Decompose W into 4 balanced base-256 int8 digits on grid 2^-33, fragment-tiled:
// Btl[s][nt][kst][ (khalf*32+col)*16 + j ].
__global__ void wslice_i8(const float* __restrict__ W, int O, int K, int KPAD,
                          int8_t* __restrict__ Btl) {
  int idx = blockIdx.x * 256 + threadIdx.x;
  if (idx >= O * KPAD) return;
  int o = idx / KPAD, f = idx % KPAD;
  long long wi = 0;
  if (f < K) wi = llround((double)W[(size_t)o * K + f] * 8589934592.0);  // 2^33
  int nt = o >> 5, c = o & 31, kst = f >> 5, kh = (f >> 4) & 1, j = f & 15;
  int NT = O >> 5, KST = KPAD >> 5;
  size_t base = (((size_t)nt * KST + kst) << 10) + (size_t)(kh * 32 + c) * 16 + j;
  size_t sstride = ((size_t)NT * KST) << 10;
  long long rem = wi;
#pragma unroll
  for (int s = 0; s < 4; ++s) {
    int d;
    if (s < 3) { d = (int)(int8_t)(rem & 0xff); rem = (rem - d) >> 8; }
    else d = (int)rem;                       // |d| <= ~52
    Btl[base + (size_t)s * sstride] = (int8_t)d;
  }
}

// ---------------- i8 MFMA slice GEMM, barrier-free per-wave pipeline ----------------
typedef const __attribute__((address_space(1))) uint32_t* gas_ptr;
typedef __attribute__((address_space(3))) uint32_t* las_ptr;
__device__ __forceinline__ void gld16(const void* g, void* l) {
  __builtin_amdgcn_global_load_lds((gas_ptr)g, (las_ptr)l, 16, 0, 0);
}

// Expand 16 spike bits -> 16 i8 (0/1) in 4 VGPRs (MFMA A-fragment k-order).
// Multiply bit-spread: (nib * 0x00204081) & 0x01010101 puts bit k of nib into
// byte k (shifted copies of a 4-bit value never overlap -> no carries).
__device__ __forceinline__ i32x4 expand16(uint32_t m) {
  const uint32_t MUL = 0x00204081u, MSK = 0x01010101u;
  uint4 v = make_uint4(
      ((m         & 0xFu) * MUL) & MSK,
      (((m >> 4)  & 0xFu) * MUL) & MSK,
      (((m >> 8)  & 0xFu) * MUL) & MSK,
      (((m >> 12) & 0xFu) * MUL) & MSK);
  return __builtin_bit_cast(i32x4, v);
}

// C[r][col] = (sum_f A_bits[r][f]*W[col][f]) + bias[col], exact-to-2^-33 via 4 i8 slices.
// 256 threads = 4 waves (wave = slice). Tile 64 rows x 64 cols. Barrier-free K-loop
// (wave-private B staging, counted vmcnt); verified rounds 12-14/17 (852us best).
template <int KPAD, int O>
__global__ __launch_bounds__(256, 4) void gemm_i8(
    const uint32_t* __restrict__ Abits, int awords, int rowBase,
    const int8_t* __restrict__ Btl, const float* __restrict__ bias,
    float* __restrict__ Cout) {
  constexpr int KST = KPAD / 32;
  constexpr int NR  = KST / 2;            // rounds (2 K-steps each), even, >= 4
  constexpr int NT  = O / 32;
  __shared__ __align__(16) char smem[32768];   // 4 waves x [2 buf][2 kk][2 nt][1KB]
  const int tid = threadIdx.x;
  const int lane = tid & 63;
  const int s = tid >> 6;                 // wave id = slice id
  const int row0 = blockIdx.x * 64;
  const int col0 = blockIdx.y * 64;
  const int nt0 = blockIdx.y * 2;
  const int lrow = lane & 31;
  const int shA = (lane >> 5) * 16;       // k-half select within a 32-bit word

  i32x16 acc[2][2] = {};

  const int rstride = awords * 4;         // A row stride in bytes
  const uint8_t* ar0 = (const uint8_t*)Abits + (size_t)(rowBase + row0 + lrow) * rstride;
  const uint8_t* ar1 = ar0 + (size_t)32 * rstride;
  const int8_t* bsrc0 = Btl + ((((size_t)s * NT + nt0) * KST) << 10) + (size_t)lane * 16;
  const int8_t* bsrc1 = Btl + ((((size_t)s * NT + nt0 + 1) * KST) << 10) + (size_t)lane * 16;
  char* sBs = smem + s * 8192;            // this wave's private region

#define STAGE(buf, r) do {                                                                 \
    gld16(bsrc0 + ((size_t)(2*(r))   << 10), sBs + (buf) * 4096 +        lane * 16);       \
    gld16(bsrc1 + ((size_t)(2*(r))   << 10), sBs + (buf) * 4096 + 1024 + lane * 16);       \
    gld16(bsrc0 + ((size_t)(2*(r)+1) << 10), sBs + (buf) * 4096 + 2048 + lane * 16);       \
    gld16(bsrc1 + ((size_t)(2*(r)+1) << 10), sBs + (buf) * 4096 + 3072 + lane * 16);       \
  } while (0)

  // ROUND r: WAITN = counted vmcnt; w* = A words (kst 2r, 2r+1) per m-block
#define ROUND(r, WAITN, w0m0, w1m0, w0m1, w1m1, DO_STAGE, DO_A4N, gnext) do {              \
    asm volatile("s_waitcnt vmcnt(" #WAITN ")" ::: "memory");                              \
    __builtin_amdgcn_sched_barrier(0);                                                     \
    const char* bb = sBs + ((r) & 1) * 4096 + lane * 16;                                   \
    uint4 b00 = *(const uint4*)(bb);                                                       \
    uint4 b01 = *(const uint4*)(bb + 1024);                                                \
    uint4 b10 = *(const uint4*)(bb + 2048);                                                \
    uint4 b11 = *(const uint4*)(bb + 3072);                                                \
    asm volatile("s_waitcnt lgkmcnt(0)" ::: "memory");                                     \
    if (DO_STAGE) STAGE((r) & 1, (r) + 2);                                                 \
    if (DO_A4N) {                                                                          \
      A40n = *(const uint4*)(ar0 + (size_t)(gnext) * 16);                                  \
      A41n = *(const uint4*)(ar1 + (size_t)(gnext) * 16);                                  \
    }                                                                                      \
    i32x4 a00 = expand16(w0m0 >> shA);  /* m0, kk0 */                                      \
    i32x4 a01 = expand16(w1m0 >> shA);  /* m0, kk1 */                                      \
    i32x4 a10 = expand16(w0m1 >> shA);  /* m1, kk0 */                                      \
    i32x4 a11 = expand16(w1m1 >> shA);  /* m1, kk1 */                                      \
    i32x4 c00 = __builtin_bit_cast(i32x4, b00), c01 = __builtin_bit_cast(i32x4, b01);      \
    i32x4 c10 = __builtin_bit_cast(i32x4, b10), c11 = __builtin_bit_cast(i32x4, b11);      \
    __builtin_amdgcn_s_setprio(1);                                                         \
    acc[0][0] = __builtin_amdgcn_mfma_i32_32x32x32_i8(a00, c00, acc[0][0], 0, 0, 0);       \
    acc[0][1] = __builtin_amdgcn_mfma_i32_32x32x32_i8(a00, c01, acc[0][1], 0, 0, 0);       \
    acc[1][0] = __builtin_amdgcn_mfma_i32_32x32x32_i8(a10, c00, acc[1][0], 0, 0, 0);       \
    acc[1][1] = __builtin_amdgcn_mfma_i32_32x32x32_i8(a10, c01, acc[1][1], 0, 0, 0);       \
    acc[0][0] = __builtin_amdgcn_mfma_i32_32x32x32_i8(a01, c10, acc[0][0], 0, 0, 0);       \
    acc[0][1] = __builtin_amdgcn_mfma_i32_32x32x32_i8(a01, c11, acc[0][1], 0, 0, 0);       \
    acc[1][0] = __builtin_amdgcn_mfma_i32_32x32x32_i8(a11, c10, acc[1][0], 0, 0, 0);       \
    acc[1][1] = __builtin_amdgcn_mfma_i32_32x32x32_i8(a11, c11, acc[1][1], 0, 0, 0);       \
    __builtin_amdgcn_s_setprio(0);                                                         \
  } while (0)

  // Prologue: 2 buffers in flight + first A pair.
  STAGE(0, 0);
  STAGE(1, 1);
  uint4 A40 = *(const uint4*)(ar0);
  uint4 A41 = *(const uint4*)(ar1);
  uint4 A40n, A41n;

  // Main: pairs g = 0 .. NR/2-2; last pair peeled (no staging, drain).
#pragma unroll 1
  for (int g = 0; g < NR / 2 - 1; ++g) {
    ROUND(2 * g,     4, A40.x, A40.y, A41.x, A41.y, true, true, g + 1);
    ROUND(2 * g + 1, 4, A40.z, A40.w, A41.z, A41.w, true, false, 0);
    A40 = A40n; A41 = A41n;
  }
  ROUND(NR - 2, 4, A40.x, A40.y, A41.x, A41.y, false, false, 0);
  ROUND(NR - 1, 0, A40.z, A40.w, A41.z, A41.w, false, false, 0);
#undef ROUND
#undef STAGE

  // Epilogue: i64 combine of the 4 slices via LDS, f32 output.
  // FULLY UNROLLED acc indices (rule #20).
  int* red = (int*)smem;   // [4][64 rows][32 cols] = 32KB
#pragma unroll
  for (int n = 0; n < 2; ++n) {
    __syncthreads();
#pragma unroll
    for (int m = 0; m < 2; ++m)
#pragma unroll
      for (int r = 0; r < 16; ++r) {
        int row = m * 32 + (r & 3) + ((r >> 2) << 3) + ((lane >> 5) << 2);
        red[(s * 64 + row) * 32 + (lane & 31)] = acc[m][n][r];
      }
    __syncthreads();
    for (int e = tid; e < 2048; e += 256) {
      int row = e >> 5, c = e & 31;
      long long v = 0;
#pragma unroll
      for (int s4 = 0; s4 < 4; ++s4)
        v += (long long)red[(s4 * 64 + row) * 32 + c] * (1LL << (8 * s4));
      int col = col0 + n * 32 + c;
      Cout[(size_t)(row0 + row) * O + col] = (float)((double)v * 0x1p-33 + (double)bias[col]);
    }
  }
}

// LIF layer 1: one block per batch row of chunk, 512 threads = H1 neurons.
__global__ __launch_bounds__(512) void lif1(const float* __restrict__ inp1,
                                            uint32_t* __restrict__ spk1, int bBase) {
  int b_local = blockIdx.x;
  int o = threadIdx.x;
  int b = bBase + b_local;
  double mem = 0.0;
  for (int t = 0; t < Tst; ++t) {
    double inp = (double)inp1[((size_t)(b_local * Tst + t)) * H1 + o];
    mem = mem + (inp - mem) / 2.0;
    bool spk = (mem >= 1.0);
    unsigned long long m = __ballot(spk);
    if ((o & 63) == 0) {
      int wv = o >> 6;
      size_t base = ((size_t)(b * Tst + t)) * (H1 / 32);
      spk1[base + wv * 2]     = (uint32_t)(m & 0xffffffffu);
      spk1[base + wv * 2 + 1] = (uint32_t)(m >> 32);
    }
    if (spk) mem = 0.0;
  }
}

// LIF layer 2: one block per batch row of chunk; final membrane out (f64).
__global__ __launch_bounds__(128) void lif2(const float* __restrict__ inp2,
                                            double* __restrict__ mem2, int bBase) {
  int b_local = blockIdx.x;
  int o = threadIdx.x;
  double mem = 0.0;
  for (int t = 0; t < Tst; ++t) {
    double inp = (double)inp2[((size_t)(b_local * Tst + t)) * H2 + o];
    mem = mem + (inp - mem) / 2.0;
    if (mem >= 1.0) mem = 0.0;
  }
  mem2[(size_t)(bBase + b_local) * H2 + o] = mem;
}

// out = mem2 @ Wd^T + bd
__global__ void finalk(const double* __restrict__ mem2, const float* __restrict__ Wd,
                       const float* __restrict__ bd, float* __restrict__ out) {
  int gid = blockIdx.x * blockDim.x + threadIdx.x;
  if (gid >= Bsz * NOUT) return;
  int b = gid / NOUT, j = gid % NOUT;
  double s = (double)bd[j];
  const double* m = mem2 + (size_t)b * H2;
  const float* wr = Wd + (size_t)j * H2;
  for (int k = 0; k < H2; ++k) s = fma(m[k], (double)wr[k], s);
  out[gid] = (float)s;
}

extern "C" void kernel_launch(void* const* d_in, const int* in_sizes, int n_in,
                              void* d_out, int out_size, void* d_ws, size_t ws_size,
                              hipStream_t stream) {
  const float* x  = (const float*)d_in[0];
  const float* W1 = (const float*)d_in[1];
  const float* b1 = (const float*)d_in[2];
  const float* W2 = (const float*)d_in[3];
  const float* b2 = (const float*)d_in[4];
  const float* Wd = (const float*)d_in[5];
  const float* bd = (const float*)d_in[6];
  float* out = (float*)d_out;

  char* ws = (char*)d_ws;
  float*    inp   = (float*)   (ws);                  // chunk inp f32 (<= 41.9MB)
  double*   mem2  = (double*)  (ws + 41943040ull);
  uint32_t* sbits = (uint32_t*)(ws + 46137344ull);
  uint32_t* spk1  = (uint32_t*)(ws + 67108864ull);
  int8_t*   Btl1  = (int8_t*)  (ws + 72351744ull);    // 4*16*64*1024
  int8_t*   Btl2  = (int8_t*)  (ws + 77594624ull);    // 4*4*16*1024

  // 1) exact Poisson spike train (bit-packed)
  spikegen4<<<dim3(Bsz), dim3(256), 0, stream>>>(x, sbits);

  // 2) weight digit decomposition (fragment-tiled, 4 slices, grid 2^-33)
  wslice_i8<<<dim3(512 * 2048 / 256), dim3(256), 0, stream>>>(W1, 512, 2000, 2048, Btl1);
  wslice_i8<<<dim3(128 * 512 / 256),  dim3(256), 0, stream>>>(W2, 128, 512, 512, Btl2);

  // 3) layer 1: 4 chunks of 20480 rows (1024 batches); tiles 64x64
  for (int c = 0; c < 4; ++c) {
    gemm_i8<2048, 512><<<dim3(320, 8), dim3(256), 0, stream>>>(
        sbits, FW, c * 20480, Btl1, b1, inp);
    lif1<<<dim3(1024), dim3(H1), 0, stream>>>(inp, spk1, c * 1024);
  }

  // 4) layer 2: 2 chunks of 40960 rows (2048 batches); tiles 64x64
  for (int c = 0; c < 2; ++c) {
    gemm_i8<512, 128><<<dim3(640, 2), dim3(256), 0, stream>>>(
        spk1, H1 / 32, c * 40960, Btl2, b2, inp);
    lif2<<<dim3(2048), dim3(H2), 0, stream>>>(inp, mem2, c * 2048);
  }

  // 5) readout
  finalk<<<dim3((Bsz * NOUT + 255) / 256), dim3(256), 0, stream>>>(mem2, Wd, bd, out);
}